// Round 4
// baseline (256.118 us; speedup 1.0000x reference)
//
#include <hip/hip_runtime.h>
#include <math.h>

#define CH  256
#define SPA 4096
#define BB  16
#define PLANE 16777216   // 16*256*4096 elements per tensor

typedef _Float16 f16x8 __attribute__((ext_vector_type(8)));
typedef _Float16 f16x4 __attribute__((ext_vector_type(4)));
typedef float    f32x4 __attribute__((ext_vector_type(4)));

__device__ __forceinline__ void gload16(const void* g, void* l) {
    __builtin_amdgcn_global_load_lds(
        (const __attribute__((address_space(1))) unsigned int*)g,
        (__attribute__((address_space(3))) unsigned int*)l, 16, 0, 0);
}

// ---------- x transpose + fp16 cvt: src[b][r][s] f32 -> dst[b][s][r] fp16 ----------
__global__ __launch_bounds__(256) void xpose_kernel(
    const float* __restrict__ src, _Float16* __restrict__ dst)
{
    __shared__ float T[64][65];
    const int t  = threadIdx.x;
    const int b  = blockIdx.x >> 8;
    const int st = (blockIdx.x >> 2) & 63;
    const int rt = blockIdx.x & 3;
    const int s0 = st << 6, r0 = rt << 6;

    #pragma unroll
    for (int p = 0; p < 4; ++p) {
        int k = (t >> 4) + (p << 4);
        float4 v = *(const float4*)(src + (((size_t)((b << 8) + r0 + k)) << 12)
                                        + s0 + ((t & 15) << 2));
        T[k][((t & 15) << 2) + 0] = v.x;
        T[k][((t & 15) << 2) + 1] = v.y;
        T[k][((t & 15) << 2) + 2] = v.z;
        T[k][((t & 15) << 2) + 3] = v.w;
    }
    __syncthreads();

    const int s  = t >> 2;
    const int kg = (t & 3) << 4;
    const size_t obase = (((size_t)((b << 12) + s0 + s)) << 8) + r0 + kg;

    f16x8 h0, h1;
    #pragma unroll
    for (int i = 0; i < 16; ++i) {
        _Float16 hv = (_Float16)T[kg + i][s];
        if (i < 8) h0[i] = hv; else h1[i - 8] = hv;
    }
    *(f16x8*)(dst + obase)     = h0;
    *(f16x8*)(dst + obase + 8) = h1;
}

// ---------- channel transpose fp16: src[b][c][s] -> dst[b][s][c] ----------
__global__ __launch_bounds__(256) void cpose_kernel(
    const _Float16* __restrict__ src, _Float16* __restrict__ dst)
{
    __shared__ _Float16 T[64][68];
    const int t  = threadIdx.x;
    const int b  = blockIdx.x >> 8;
    const int st = (blockIdx.x >> 2) & 63;
    const int ct = blockIdx.x & 3;
    const int s0 = st << 6, c0 = ct << 6;

    #pragma unroll
    for (int p = 0; p < 4; ++p) {
        int fi = (p << 8) + t;
        int r = fi >> 4, s4 = (fi & 15) << 2;
        f16x4 v = *(const f16x4*)(src + (((size_t)((b << 8) + c0 + r)) << 12) + s0 + s4);
        *(f16x4*)&T[r][s4] = v;
    }
    __syncthreads();

    const int s  = t >> 2;
    const int cg = (t & 3) << 4;
    f16x8 h0, h1;
    #pragma unroll
    for (int i = 0; i < 16; ++i) {
        _Float16 hv = T[cg + i][s];
        if (i < 8) h0[i] = hv; else h1[i - 8] = hv;
    }
    const size_t obase = (((size_t)((b << 12) + s0 + s)) << 8) + c0 + cg;
    *(f16x8*)(dst + obase)     = h0;
    *(f16x8*)(dst + obase + 8) = h1;
}

// ---------- weight cvt: 4 matrices [o][k] f32 -> fp16 ----------
__global__ __launch_bounds__(256) void wcvt_kernel(
    const float* __restrict__ w0, const float* __restrict__ w1,
    const float* __restrict__ w2, const float* __restrict__ w3,
    _Float16* __restrict__ dst)
{
    const int idx = blockIdx.x * 256 + threadIdx.x;
    dst[idx]             = (_Float16)w0[idx];
    dst[65536 + idx]     = (_Float16)w1[idx];
    dst[131072 + idx]    = (_Float16)w2[idx];
    dst[196608 + idx]    = (_Float16)w3[idx];
}

// ---------- fp16 MFMA GEMM conv: out[b][o][s] = W[o][:].X[b][s][:] + bias ----------
// NM=3: m = blockIdx.x % 3 (fastest-varying -> blocks sharing an A tile are
// dispatch-adjacent; L3 absorbs the re-reads). NM=1: single matrix.
template<int NM, bool OUTF16>
__global__ __launch_bounds__(256) void gemm16_kernel(
    const _Float16* __restrict__ xT, const _Float16* __restrict__ wc,
    const float* __restrict__ bias0, const float* __restrict__ bias1,
    const float* __restrict__ bias2, void* __restrict__ outp)
{
    __shared__ _Float16 S[8192];
    _Float16* sA = S;
    _Float16* sB = S + 4096;

    int m, r_;
    if (NM == 3) { m = blockIdx.x % 3; r_ = blockIdx.x / 3; }
    else         { m = 0;              r_ = blockIdx.x; }
    const _Float16* wp = wc + m * 65536;
    const float* bias = (m == 0) ? bias0 : ((m == 1) ? bias1 : bias2);

    const int tid = threadIdx.x;
    const int w = tid >> 6, lane = tid & 63, quad = lane >> 4, li = lane & 15;
    const int wx = w & 1, wy = w >> 1;
    const int ot    = r_ & 1;
    const int stile = (r_ >> 1) & 31;
    const int b     = r_ >> 6;
    const int s0 = stile << 7, o0 = ot << 7;

    f32x4 acc[4][4];
    #pragma unroll
    for (int t2 = 0; t2 < 4; ++t2)
        #pragma unroll
        for (int u = 0; u < 4; ++u) acc[t2][u] = (f32x4){0.f, 0.f, 0.f, 0.f};

    const int rr = lane >> 2, cc = (lane & 3) << 3;

    for (int kb = 0; kb < CH; kb += 32) {
        __syncthreads();
        #pragma unroll
        for (int j = 0; j < 32; j += 16) {
            const int r = (w << 5) + j + rr;
            const size_t ga = (((size_t)((b << 12) + s0 + r)) << 8) + kb + cc;
            const size_t gb = ((size_t)(o0 + r) << 8) + kb + cc;
            const int lo_ = ((w << 5) + j) * 32 + lane * 8;
            gload16(xT + ga, sA + lo_);
            gload16(wp + gb, sB + lo_);
        }
        __syncthreads();

        f16x8 a[4], bfr[4];
        #pragma unroll
        for (int t2 = 0; t2 < 4; ++t2) {
            a[t2]   = *(const f16x8*)(sA + ((wy << 6) + (t2 << 4) + li) * 32 + (quad << 3));
            bfr[t2] = *(const f16x8*)(sB + ((wx << 6) + (t2 << 4) + li) * 32 + (quad << 3));
        }
        #pragma unroll
        for (int t2 = 0; t2 < 4; ++t2)
            #pragma unroll
            for (int u = 0; u < 4; ++u)
                acc[t2][u] = __builtin_amdgcn_mfma_f32_16x16x32_f16(a[t2], bfr[u], acc[t2][u], 0, 0, 0);
    }

    #pragma unroll
    for (int u = 0; u < 4; ++u) {
        const int o = o0 + (wx << 6) + (u << 4) + li;
        const float bz = bias[o];
        #pragma unroll
        for (int t2 = 0; t2 < 4; ++t2) {
            const int s = s0 + (wy << 6) + (t2 << 4) + (quad << 2);
            const size_t off = (((size_t)((b << 8) + o)) << 12) + s;
            f32x4 v = acc[t2][u];
            if (OUTF16) {
                _Float16* ob = (_Float16*)outp + (size_t)m * PLANE;
                f16x4 pv;
                pv[0] = (_Float16)(v[0] + bz); pv[1] = (_Float16)(v[1] + bz);
                pv[2] = (_Float16)(v[2] + bz); pv[3] = (_Float16)(v[3] + bz);
                *(f16x4*)(ob + off) = pv;
            } else {
                float* of = (float*)outp;
                float4 pv = {v[0] + bz, v[1] + bz, v[2] + bz, v[3] + bz};
                *(float4*)(of + off) = pv;
            }
        }
    }
}

// ---------- MFMA attention: one block per (b,c) ----------
// S = F^T G via MFMA (operands transposed via MFMA x identity), softmax done
// entirely in registers (shfl_xor row reductions), P^T written straight from
// registers (swizzled), O = H . P via MFMA. LDS 46080 B -> 3 blocks/CU.
__global__ __launch_bounds__(256) void attn_mfma_kernel(
    const _Float16* __restrict__ fx, const _Float16* __restrict__ gx,
    const _Float16* __restrict__ hx, _Float16* __restrict__ ob)
{
    __shared__ _Float16 L[23040];           // 46080 B
    const int FT = 0, GT = 4608, HM = 9216; // pitch-72 64-row panels
    const int FR = 13824, GR = 18432;       // raw staging
    const int PT = 13824;                   // P^T aliases FR (dead post-transpose)

    const int t = threadIdx.x;
    const int wave = t >> 6, lane = t & 63, q = lane >> 4, li = lane & 15;
    const int bc = blockIdx.x;
    const _Float16* Fp = fx + (size_t)bc * SPA;
    const _Float16* Gp = gx + (size_t)bc * SPA;
    const _Float16* Hp = hx + (size_t)bc * SPA;
    _Float16* Op = ob + (size_t)bc * SPA;

    // stage F,G,H (pitch-72 rows, b128 writes)
    #pragma unroll
    for (int p = 0; p < 2; ++p) {
        int ci = t + (p << 8);
        int h = ci >> 3, w8 = (ci & 7) << 3;
        *(f16x8*)&L[FR + h * 72 + w8] = *(const f16x8*)(Fp + h * 64 + w8);
        *(f16x8*)&L[GR + h * 72 + w8] = *(const f16x8*)(Gp + h * 64 + w8);
        *(f16x8*)&L[HM + h * 72 + w8] = *(const f16x8*)(Hp + h * 64 + w8);
    }
    __syncthreads();

    // transpose F,G via MFMA x identity: D = A*I lands A in C-layout
    {
        const int src = (wave < 2) ? FR : GR;
        const int dst = (wave < 2) ? FT : GT;
        const int mtb = (wave & 1) << 1;
        f16x8 id0, id1;
        #pragma unroll
        for (int j = 0; j < 8; ++j) {
            id0[j] = (_Float16)(((q << 3) + j == li)      ? 1.0f : 0.0f);
            id1[j] = (_Float16)(((q << 3) + j == li + 16) ? 1.0f : 0.0f);
        }
        #pragma unroll
        for (int mi = 0; mi < 2; ++mi) {
            const int mt = mtb + mi;
            f16x8 a0 = *(const f16x8*)&L[src + (mt * 16 + li) * 72 + (q << 3)];
            f16x8 a1 = *(const f16x8*)&L[src + (mt * 16 + li) * 72 + 32 + (q << 3)];
            #pragma unroll
            for (int nt = 0; nt < 4; ++nt) {
                f32x4 d = {0.f, 0.f, 0.f, 0.f};
                d = __builtin_amdgcn_mfma_f32_16x16x32_f16(
                        (nt < 2) ? a0 : a1, (nt & 1) ? id1 : id0, d, 0, 0, 0);
                f16x4 e;
                e[0] = (_Float16)d[0]; e[1] = (_Float16)d[1];
                e[2] = (_Float16)d[2]; e[3] = (_Float16)d[3];
                *(f16x4*)&L[dst + (nt * 16 + li) * 72 + mt * 16 + (q << 2)] = e;
            }
        }
    }
    __syncthreads();

    // S-GEMM (wave owns S rows [wave*16, wave*16+16)) + register softmax
    {
        f16x8 a0 = *(const f16x8*)&L[FT + (wave * 16 + li) * 72 + (q << 3)];
        f16x8 a1 = *(const f16x8*)&L[FT + (wave * 16 + li) * 72 + 32 + (q << 3)];
        f32x4 s_[4];
        #pragma unroll
        for (int nt = 0; nt < 4; ++nt) {
            f16x8 b0 = *(const f16x8*)&L[GT + (nt * 16 + li) * 72 + (q << 3)];
            f16x8 b1 = *(const f16x8*)&L[GT + (nt * 16 + li) * 72 + 32 + (q << 3)];
            f32x4 acc = {0.f, 0.f, 0.f, 0.f};
            acc = __builtin_amdgcn_mfma_f32_16x16x32_f16(a0, b0, acc, 0, 0, 0);
            acc = __builtin_amdgcn_mfma_f32_16x16x32_f16(a1, b1, acc, 0, 0, 0);
            s_[nt] = acc;
        }
        // row r lives in regs s_[0..3][r] across the 16 li lanes of this quad
        float mx[4], sm[4];
        #pragma unroll
        for (int r = 0; r < 4; ++r) {
            float m0 = fmaxf(fmaxf(s_[0][r], s_[1][r]), fmaxf(s_[2][r], s_[3][r]));
            m0 = fmaxf(m0, __shfl_xor(m0, 1));
            m0 = fmaxf(m0, __shfl_xor(m0, 2));
            m0 = fmaxf(m0, __shfl_xor(m0, 4));
            m0 = fmaxf(m0, __shfl_xor(m0, 8));
            mx[r] = m0;
        }
        #pragma unroll
        for (int nt = 0; nt < 4; ++nt)
            #pragma unroll
            for (int r = 0; r < 4; ++r)
                s_[nt][r] = __expf(s_[nt][r] - mx[r]);
        #pragma unroll
        for (int r = 0; r < 4; ++r) {
            float s0 = (s_[0][r] + s_[1][r]) + (s_[2][r] + s_[3][r]);
            s0 += __shfl_xor(s0, 1);
            s0 += __shfl_xor(s0, 2);
            s0 += __shfl_xor(s0, 4);
            s0 += __shfl_xor(s0, 8);
            sm[r] = 1.f / s0;
        }
        // write P^T (chunk-XOR swizzle on the w index)
        #pragma unroll
        for (int nt = 0; nt < 4; ++nt) {
            const int v  = nt * 16 + li;
            const int sw = ((v >> 3) & 7) << 3;
            #pragma unroll
            for (int r = 0; r < 4; ++r) {
                const int w = wave * 16 + (q << 2) + r;
                L[PT + v * 72 + (w ^ sw)] = (_Float16)(s_[nt][r] * sm[r]);
            }
        }
    }
    __syncthreads();

    // O-GEMM: O[h][v] = sum_w H[h][w] P[w][v]
    {
        f16x8 a0 = *(const f16x8*)&L[HM + (wave * 16 + li) * 72 + (q << 3)];
        f16x8 a1 = *(const f16x8*)&L[HM + (wave * 16 + li) * 72 + 32 + (q << 3)];
        #pragma unroll
        for (int nt = 0; nt < 4; ++nt) {
            const int v  = nt * 16 + li;
            const int sw = ((v >> 3) & 7) << 3;
            f16x8 b0 = *(const f16x8*)&L[PT + v * 72 + ((q << 3) ^ sw)];
            f16x8 b1 = *(const f16x8*)&L[PT + v * 72 + ((32 + (q << 3)) ^ sw)];
            f32x4 acc = {0.f, 0.f, 0.f, 0.f};
            acc = __builtin_amdgcn_mfma_f32_16x16x32_f16(a0, b0, acc, 0, 0, 0);
            acc = __builtin_amdgcn_mfma_f32_16x16x32_f16(a1, b1, acc, 0, 0, 0);
            #pragma unroll
            for (int r = 0; r < 4; ++r)
                Op[(wave * 16 + (q << 2) + r) * 64 + v] = (_Float16)acc[r];
        }
    }
}

extern "C" void kernel_launch(void* const* d_in, const int* in_sizes, int n_in,
                              void* d_out, int out_size, void* d_ws, size_t ws_size,
                              hipStream_t stream)
{
    const float* x  = (const float*)d_in[0];
    const float* wf = (const float*)d_in[1];
    const float* bf = (const float*)d_in[2];
    const float* wg = (const float*)d_in[3];
    const float* bg = (const float*)d_in[4];
    const float* wh = (const float*)d_in[5];
    const float* bh = (const float*)d_in[6];
    const float* wv = (const float*)d_in[7];
    const float* bv = (const float*)d_in[8];

    char* base = (char*)d_ws;
    const size_t MB = 1ull << 20;
    _Float16* xT  = (_Float16*)base;               // [0,32)  MiB
    _Float16* fxb = (_Float16*)(base + 32 * MB);   // [32,64)
    _Float16* gxb = (_Float16*)(base + 64 * MB);   // [64,96)
    _Float16* hxb = (_Float16*)(base + 96 * MB);   // [96,128)
    _Float16* ob  = (_Float16*)(base + 128 * MB);  // [128,160)
    _Float16* obT = (_Float16*)base;               // [0,32) — xT dead after convs
    _Float16* wc  = (_Float16*)(base + 160 * MB);  // 512 KB

    dim3 blk(256);
    xpose_kernel<<<4096, blk, 0, stream>>>(x, xT);
    wcvt_kernel<<<256, blk, 0, stream>>>(wf, wg, wh, wv, wc);

    gemm16_kernel<3, true><<<dim3(3072), blk, 0, stream>>>(
        xT, wc, bf, bg, bh, fxb);

    attn_mfma_kernel<<<4096, blk, 0, stream>>>(fxb, gxb, hxb, ob);

    cpose_kernel<<<4096, blk, 0, stream>>>(ob, obT);

    gemm16_kernel<1, false><<<dim3(1024), blk, 0, stream>>>(
        obT, wc + 196608, bv, bv, bv, d_out);
}

// Round 7
// 249.456 us; speedup vs baseline: 1.0267x; 1.0267x over previous
//
#include <hip/hip_runtime.h>
#include <math.h>

#define CH  256
#define SPA 4096
#define BB  16
#define PLANE 16777216   // 16*256*4096 elements per tensor

typedef _Float16 f16x8 __attribute__((ext_vector_type(8)));
typedef _Float16 f16x4 __attribute__((ext_vector_type(4)));
typedef float    f32x4 __attribute__((ext_vector_type(4)));

__device__ __forceinline__ void gload16(const void* g, void* l) {
    __builtin_amdgcn_global_load_lds(
        (const __attribute__((address_space(1))) unsigned int*)g,
        (__attribute__((address_space(3))) unsigned int*)l, 16, 0, 0);
}

// ---------- x transpose + fp16 cvt: src[b][r][s] f32 -> dst[b][s][r] fp16 ----------
__global__ __launch_bounds__(256) void xpose_kernel(
    const float* __restrict__ src, _Float16* __restrict__ dst)
{
    __shared__ float T[64][65];
    const int t  = threadIdx.x;
    const int b  = blockIdx.x >> 8;
    const int st = (blockIdx.x >> 2) & 63;
    const int rt = blockIdx.x & 3;
    const int s0 = st << 6, r0 = rt << 6;

    #pragma unroll
    for (int p = 0; p < 4; ++p) {
        int k = (t >> 4) + (p << 4);
        float4 v = *(const float4*)(src + (((size_t)((b << 8) + r0 + k)) << 12)
                                        + s0 + ((t & 15) << 2));
        T[k][((t & 15) << 2) + 0] = v.x;
        T[k][((t & 15) << 2) + 1] = v.y;
        T[k][((t & 15) << 2) + 2] = v.z;
        T[k][((t & 15) << 2) + 3] = v.w;
    }
    __syncthreads();

    const int s  = t >> 2;
    const int kg = (t & 3) << 4;
    const size_t obase = (((size_t)((b << 12) + s0 + s)) << 8) + r0 + kg;

    f16x8 h0, h1;
    #pragma unroll
    for (int i = 0; i < 16; ++i) {
        _Float16 hv = (_Float16)T[kg + i][s];
        if (i < 8) h0[i] = hv; else h1[i - 8] = hv;
    }
    *(f16x8*)(dst + obase)     = h0;
    *(f16x8*)(dst + obase + 8) = h1;
}

// ---------- channel transpose fp16: src[b][c][s] -> dst[b][s][c] ----------
__global__ __launch_bounds__(256) void cpose_kernel(
    const _Float16* __restrict__ src, _Float16* __restrict__ dst)
{
    __shared__ _Float16 T[64][68];
    const int t  = threadIdx.x;
    const int b  = blockIdx.x >> 8;
    const int st = (blockIdx.x >> 2) & 63;
    const int ct = blockIdx.x & 3;
    const int s0 = st << 6, c0 = ct << 6;

    #pragma unroll
    for (int p = 0; p < 4; ++p) {
        int fi = (p << 8) + t;
        int r = fi >> 4, s4 = (fi & 15) << 2;
        f16x4 v = *(const f16x4*)(src + (((size_t)((b << 8) + c0 + r)) << 12) + s0 + s4);
        *(f16x4*)&T[r][s4] = v;
    }
    __syncthreads();

    const int s  = t >> 2;
    const int cg = (t & 3) << 4;
    f16x8 h0, h1;
    #pragma unroll
    for (int i = 0; i < 16; ++i) {
        _Float16 hv = T[cg + i][s];
        if (i < 8) h0[i] = hv; else h1[i - 8] = hv;
    }
    const size_t obase = (((size_t)((b << 12) + s0 + s)) << 8) + c0 + cg;
    *(f16x8*)(dst + obase)     = h0;
    *(f16x8*)(dst + obase + 8) = h1;
}

// ---------- weight cvt: 4 matrices [o][k] f32 -> fp16 ----------
__global__ __launch_bounds__(256) void wcvt_kernel(
    const float* __restrict__ w0, const float* __restrict__ w1,
    const float* __restrict__ w2, const float* __restrict__ w3,
    _Float16* __restrict__ dst)
{
    const int idx = blockIdx.x * 256 + threadIdx.x;
    dst[idx]             = (_Float16)w0[idx];
    dst[65536 + idx]     = (_Float16)w1[idx];
    dst[131072 + idx]    = (_Float16)w2[idx];
    dst[196608 + idx]    = (_Float16)w3[idx];
}

// ---------- fused f/g/h conv: one block = 128s x 64o for ALL 3 matrices ----------
// A-tile staged once per K-step serves 3 B-panels: 3x fewer A fetches and
// 24 MFMAs/wave per barrier-drain (vs 16) to amortize the vmcnt(0) latency.
// Grid: 4 o-tiles x 32 s-tiles x 16 b = 2048 blocks (ot fastest).
__global__ __launch_bounds__(256) void gemm_fgh_kernel(
    const _Float16* __restrict__ xT, const _Float16* __restrict__ wc,
    const float* __restrict__ bias0, const float* __restrict__ bias1,
    const float* __restrict__ bias2, _Float16* __restrict__ outp)
{
    __shared__ _Float16 S[10240];          // A: 128x32 (4096) + 3x B: 64x32 (2048 each)
    _Float16* sA = S;

    const int tid = threadIdx.x;
    const int w = tid >> 6, lane = tid & 63, q = lane >> 4, li = lane & 15;
    const int r_ = blockIdx.x;
    const int ot    = r_ & 3;               // 4 o-tiles of 64
    const int stile = (r_ >> 2) & 31;       // 32 s-tiles of 128
    const int b     = r_ >> 7;              // 16 batches
    const int s0 = stile << 7, o0 = ot << 6;

    const float* biases[3] = {bias0, bias1, bias2};

    f32x4 acc[3][4][2];
    #pragma unroll
    for (int m = 0; m < 3; ++m)
        #pragma unroll
        for (int t2 = 0; t2 < 4; ++t2)
            #pragma unroll
            for (int u = 0; u < 2; ++u) acc[m][t2][u] = (f32x4){0.f, 0.f, 0.f, 0.f};

    const int rr = tid >> 2;            // 0..63
    const int cc = (tid & 3) << 3;      // k-chunk

    const int n0 = (w & 1) << 5;        // wave o-offset (32)
    const int m0 = (w >> 1) << 6;       // wave s-offset (64)

    for (int kb = 0; kb < CH; kb += 32) {
        __syncthreads();
        {
            const size_t ga = (((size_t)((b << 12) + s0 + rr)) << 8) + kb + cc;
            gload16(xT + ga, sA + tid * 8);                       // A rows 0..63
            gload16(xT + ga + (64ull << 8), sA + 2048 + tid * 8); // A rows 64..127
            #pragma unroll
            for (int m = 0; m < 3; ++m) {
                const size_t gb = (((size_t)(o0 + rr)) << 8) + m * 65536 + kb + cc;
                gload16(wc + gb, S + 4096 + m * 2048 + tid * 8);
            }
        }
        __syncthreads();

        f16x8 a[4];
        #pragma unroll
        for (int t2 = 0; t2 < 4; ++t2)
            a[t2] = *(const f16x8*)(sA + (m0 + (t2 << 4) + li) * 32 + (q << 3));

        #pragma unroll
        for (int m = 0; m < 3; ++m) {
            const _Float16* sB = S + 4096 + m * 2048;
            f16x8 b0 = *(const f16x8*)(sB + (n0 + li) * 32 + (q << 3));
            f16x8 b1 = *(const f16x8*)(sB + (n0 + 16 + li) * 32 + (q << 3));
            #pragma unroll
            for (int t2 = 0; t2 < 4; ++t2) {
                acc[m][t2][0] = __builtin_amdgcn_mfma_f32_16x16x32_f16(a[t2], b0, acc[m][t2][0], 0, 0, 0);
                acc[m][t2][1] = __builtin_amdgcn_mfma_f32_16x16x32_f16(a[t2], b1, acc[m][t2][1], 0, 0, 0);
            }
        }
    }

    #pragma unroll
    for (int m = 0; m < 3; ++m) {
        _Float16* ob = outp + (size_t)m * PLANE;
        #pragma unroll
        for (int u = 0; u < 2; ++u) {
            const int o = o0 + n0 + (u << 4) + li;
            const float bz = biases[m][o];
            #pragma unroll
            for (int t2 = 0; t2 < 4; ++t2) {
                const int s = s0 + m0 + (t2 << 4) + (q << 2);
                const size_t off = (((size_t)((b << 8) + o)) << 12) + s;
                f32x4 v = acc[m][t2][u];
                f16x4 pv;
                pv[0] = (_Float16)(v[0] + bz); pv[1] = (_Float16)(v[1] + bz);
                pv[2] = (_Float16)(v[2] + bz); pv[3] = (_Float16)(v[3] + bz);
                *(f16x4*)(ob + off) = pv;
            }
        }
    }
}

// ---------- final conv (single matrix, f32 out), 128s x 128o ----------
__global__ __launch_bounds__(256) void gemm16_kernel(
    const _Float16* __restrict__ xT, const _Float16* __restrict__ wp,
    const float* __restrict__ bias, float* __restrict__ outp)
{
    __shared__ _Float16 S[8192];
    _Float16* sA = S;
    _Float16* sB = S + 4096;

    const int tid = threadIdx.x;
    const int w = tid >> 6, lane = tid & 63, quad = lane >> 4, li = lane & 15;
    const int wx = w & 1, wy = w >> 1;
    const int r_ = blockIdx.x;
    const int ot    = r_ & 1;
    const int stile = (r_ >> 1) & 31;
    const int b     = r_ >> 6;
    const int s0 = stile << 7, o0 = ot << 7;

    f32x4 acc[4][4];
    #pragma unroll
    for (int t2 = 0; t2 < 4; ++t2)
        #pragma unroll
        for (int u = 0; u < 4; ++u) acc[t2][u] = (f32x4){0.f, 0.f, 0.f, 0.f};

    const int rr = lane >> 2, cc = (lane & 3) << 3;

    for (int kb = 0; kb < CH; kb += 32) {
        __syncthreads();
        #pragma unroll
        for (int j = 0; j < 32; j += 16) {
            const int r = (w << 5) + j + rr;
            const size_t ga = (((size_t)((b << 12) + s0 + r)) << 8) + kb + cc;
            const size_t gb = ((size_t)(o0 + r) << 8) + kb + cc;
            const int lo_ = ((w << 5) + j) * 32 + lane * 8;
            gload16(xT + ga, sA + lo_);
            gload16(wp + gb, sB + lo_);
        }
        __syncthreads();

        f16x8 a[4], bfr[4];
        #pragma unroll
        for (int t2 = 0; t2 < 4; ++t2) {
            a[t2]   = *(const f16x8*)(sA + ((wy << 6) + (t2 << 4) + li) * 32 + (quad << 3));
            bfr[t2] = *(const f16x8*)(sB + ((wx << 6) + (t2 << 4) + li) * 32 + (quad << 3));
        }
        #pragma unroll
        for (int t2 = 0; t2 < 4; ++t2)
            #pragma unroll
            for (int u = 0; u < 4; ++u)
                acc[t2][u] = __builtin_amdgcn_mfma_f32_16x16x32_f16(a[t2], bfr[u], acc[t2][u], 0, 0, 0);
    }

    #pragma unroll
    for (int u = 0; u < 4; ++u) {
        const int o = o0 + (wx << 6) + (u << 4) + li;
        const float bz = bias[o];
        #pragma unroll
        for (int t2 = 0; t2 < 4; ++t2) {
            const int s = s0 + (wy << 6) + (t2 << 4) + (quad << 2);
            const size_t off = (((size_t)((b << 8) + o)) << 12) + s;
            f32x4 v = acc[t2][u];
            float4 pv = {v[0] + bz, v[1] + bz, v[2] + bz, v[3] + bz};
            *(float4*)(outp + off) = pv;
        }
    }
}

// ---------- MFMA attention: one block per (b,c) ----------
__global__ __launch_bounds__(256) void attn_mfma_kernel(
    const _Float16* __restrict__ fx, const _Float16* __restrict__ gx,
    const _Float16* __restrict__ hx, _Float16* __restrict__ ob)
{
    __shared__ _Float16 L[23040];           // 46080 B
    const int FT = 0, GT = 4608, HM = 9216; // pitch-72 64-row panels
    const int FR = 13824, GR = 18432;       // raw staging
    const int PT = 13824;                   // P^T aliases FR

    const int t = threadIdx.x;
    const int wave = t >> 6, lane = t & 63, q = lane >> 4, li = lane & 15;
    const int bc = blockIdx.x;
    const _Float16* Fp = fx + (size_t)bc * SPA;
    const _Float16* Gp = gx + (size_t)bc * SPA;
    const _Float16* Hp = hx + (size_t)bc * SPA;
    _Float16* Op = ob + (size_t)bc * SPA;

    #pragma unroll
    for (int p = 0; p < 2; ++p) {
        int ci = t + (p << 8);
        int h = ci >> 3, w8 = (ci & 7) << 3;
        *(f16x8*)&L[FR + h * 72 + w8] = *(const f16x8*)(Fp + h * 64 + w8);
        *(f16x8*)&L[GR + h * 72 + w8] = *(const f16x8*)(Gp + h * 64 + w8);
        *(f16x8*)&L[HM + h * 72 + w8] = *(const f16x8*)(Hp + h * 64 + w8);
    }
    __syncthreads();

    // transpose F,G via MFMA x identity
    {
        const int src = (wave < 2) ? FR : GR;
        const int dst = (wave < 2) ? FT : GT;
        const int mtb = (wave & 1) << 1;
        f16x8 id0, id1;
        #pragma unroll
        for (int j = 0; j < 8; ++j) {
            id0[j] = (_Float16)(((q << 3) + j == li)      ? 1.0f : 0.0f);
            id1[j] = (_Float16)(((q << 3) + j == li + 16) ? 1.0f : 0.0f);
        }
        #pragma unroll
        for (int mi = 0; mi < 2; ++mi) {
            const int mt = mtb + mi;
            f16x8 a0 = *(const f16x8*)&L[src + (mt * 16 + li) * 72 + (q << 3)];
            f16x8 a1 = *(const f16x8*)&L[src + (mt * 16 + li) * 72 + 32 + (q << 3)];
            #pragma unroll
            for (int nt = 0; nt < 4; ++nt) {
                f32x4 d = {0.f, 0.f, 0.f, 0.f};
                d = __builtin_amdgcn_mfma_f32_16x16x32_f16(
                        (nt < 2) ? a0 : a1, (nt & 1) ? id1 : id0, d, 0, 0, 0);
                f16x4 e;
                e[0] = (_Float16)d[0]; e[1] = (_Float16)d[1];
                e[2] = (_Float16)d[2]; e[3] = (_Float16)d[3];
                *(f16x4*)&L[dst + (nt * 16 + li) * 72 + mt * 16 + (q << 2)] = e;
            }
        }
    }
    __syncthreads();

    // S-GEMM + register softmax
    {
        f16x8 a0 = *(const f16x8*)&L[FT + (wave * 16 + li) * 72 + (q << 3)];
        f16x8 a1 = *(const f16x8*)&L[FT + (wave * 16 + li) * 72 + 32 + (q << 3)];
        f32x4 s_[4];
        #pragma unroll
        for (int nt = 0; nt < 4; ++nt) {
            f16x8 b0 = *(const f16x8*)&L[GT + (nt * 16 + li) * 72 + (q << 3)];
            f16x8 b1 = *(const f16x8*)&L[GT + (nt * 16 + li) * 72 + 32 + (q << 3)];
            f32x4 acc = {0.f, 0.f, 0.f, 0.f};
            acc = __builtin_amdgcn_mfma_f32_16x16x32_f16(a0, b0, acc, 0, 0, 0);
            acc = __builtin_amdgcn_mfma_f32_16x16x32_f16(a1, b1, acc, 0, 0, 0);
            s_[nt] = acc;
        }
        float mx[4], sm[4];
        #pragma unroll
        for (int r = 0; r < 4; ++r) {
            float m0 = fmaxf(fmaxf(s_[0][r], s_[1][r]), fmaxf(s_[2][r], s_[3][r]));
            m0 = fmaxf(m0, __shfl_xor(m0, 1));
            m0 = fmaxf(m0, __shfl_xor(m0, 2));
            m0 = fmaxf(m0, __shfl_xor(m0, 4));
            m0 = fmaxf(m0, __shfl_xor(m0, 8));
            mx[r] = m0;
        }
        #pragma unroll
        for (int nt = 0; nt < 4; ++nt)
            #pragma unroll
            for (int r = 0; r < 4; ++r)
                s_[nt][r] = __expf(s_[nt][r] - mx[r]);
        #pragma unroll
        for (int r = 0; r < 4; ++r) {
            float s0 = (s_[0][r] + s_[1][r]) + (s_[2][r] + s_[3][r]);
            s0 += __shfl_xor(s0, 1);
            s0 += __shfl_xor(s0, 2);
            s0 += __shfl_xor(s0, 4);
            s0 += __shfl_xor(s0, 8);
            sm[r] = 1.f / s0;
        }
        #pragma unroll
        for (int nt = 0; nt < 4; ++nt) {
            const int v  = nt * 16 + li;
            const int sw = ((v >> 3) & 7) << 3;
            #pragma unroll
            for (int r = 0; r < 4; ++r) {
                const int w = wave * 16 + (q << 2) + r;
                L[PT + v * 72 + (w ^ sw)] = (_Float16)(s_[nt][r] * sm[r]);
            }
        }
    }
    __syncthreads();

    // O-GEMM
    {
        f16x8 a0 = *(const f16x8*)&L[HM + (wave * 16 + li) * 72 + (q << 3)];
        f16x8 a1 = *(const f16x8*)&L[HM + (wave * 16 + li) * 72 + 32 + (q << 3)];
        #pragma unroll
        for (int nt = 0; nt < 4; ++nt) {
            const int v  = nt * 16 + li;
            const int sw = ((v >> 3) & 7) << 3;
            f16x8 b0 = *(const f16x8*)&L[PT + v * 72 + ((q << 3) ^ sw)];
            f16x8 b1 = *(const f16x8*)&L[PT + v * 72 + ((32 + (q << 3)) ^ sw)];
            f32x4 acc = {0.f, 0.f, 0.f, 0.f};
            acc = __builtin_amdgcn_mfma_f32_16x16x32_f16(a0, b0, acc, 0, 0, 0);
            acc = __builtin_amdgcn_mfma_f32_16x16x32_f16(a1, b1, acc, 0, 0, 0);
            #pragma unroll
            for (int r = 0; r < 4; ++r)
                Op[(wave * 16 + (q << 2) + r) * 64 + v] = (_Float16)acc[r];
        }
    }
}

extern "C" void kernel_launch(void* const* d_in, const int* in_sizes, int n_in,
                              void* d_out, int out_size, void* d_ws, size_t ws_size,
                              hipStream_t stream)
{
    const float* x  = (const float*)d_in[0];
    const float* wf = (const float*)d_in[1];
    const float* bf = (const float*)d_in[2];
    const float* wg = (const float*)d_in[3];
    const float* bg = (const float*)d_in[4];
    const float* wh = (const float*)d_in[5];
    const float* bh = (const float*)d_in[6];
    const float* wv = (const float*)d_in[7];
    const float* bv = (const float*)d_in[8];

    char* base = (char*)d_ws;
    const size_t MB = 1ull << 20;
    _Float16* xT  = (_Float16*)base;               // [0,32)  MiB
    _Float16* fxb = (_Float16*)(base + 32 * MB);   // [32,64) (f), g [64,96), h [96,128)
    _Float16* ob  = (_Float16*)(base + 128 * MB);  // [128,160)
    _Float16* obT = (_Float16*)base;               // [0,32) — xT dead after convs
    _Float16* wc  = (_Float16*)(base + 160 * MB);  // 512 KB

    _Float16* gxb = fxb + PLANE;
    _Float16* hxb = gxb + PLANE;

    dim3 blk(256);
    xpose_kernel<<<4096, blk, 0, stream>>>(x, xT);
    wcvt_kernel<<<256, blk, 0, stream>>>(wf, wg, wh, wv, wc);

    gemm_fgh_kernel<<<2048, blk, 0, stream>>>(xT, wc, bf, bg, bh, fxb);

    attn_mfma_kernel<<<4096, blk, 0, stream>>>(fxb, gxb, hxb, ob);

    cpose_kernel<<<4096, blk, 0, stream>>>(ob, obT);

    gemm16_kernel<<<1024, blk, 0, stream>>>(obT, wc + 196608, bv, (float*)d_out);
}